// Round 10
// baseline (561.729 us; speedup 1.0000x reference)
//
#include <hip/hip_runtime.h>
#include <math.h>

// ---- problem constants ----
#define BB 2
#define DD 256
#define NH 8
#define DH 32
#define NPNP 4
#define LV 4
#define NQ 4096
#define NL 6
#define DFF 1024
#define SS 21760   // 128*128 + 64*64 + 32*32 + 16*16

typedef short v8s __attribute__((ext_vector_type(8)));
typedef float v4f __attribute__((ext_vector_type(4)));

__device__ __forceinline__ ushort f2b(float f) {
    union { float f; unsigned u; } v; v.f = f;
    unsigned r = v.u + 0x7fffu + ((v.u >> 16) & 1u);
    return (ushort)(r >> 16);
}

__device__ __constant__ int c_dims[4]   = {128, 64, 32, 16};
__device__ __constant__ int c_starts[4] = {0, 16384, 20480, 21504};
__device__ __constant__ int c_hw[4]     = {16384, 4096, 1024, 256};

// ------------------------------------------------------------------
// flatten all 4 levels: src_l (B, D, H, W) f32 -> src_flat (B, S, D) bf16
// ------------------------------------------------------------------
__global__ __launch_bounds__(256) void flatten_all_kernel(
    const float* __restrict__ s0p, const float* __restrict__ s1p,
    const float* __restrict__ s2p, const float* __restrict__ s3p,
    ushort* __restrict__ dst)
{
    __shared__ float tile[64][65];
    int bx = blockIdx.x;
    int l, ls;
    if (bx < 256)      { l = 0; ls = bx; }
    else if (bx < 320) { l = 1; ls = bx - 256; }
    else if (bx < 336) { l = 2; ls = bx - 320; }
    else               { l = 3; ls = bx - 336; }
    const float* srcs[4] = {s0p, s1p, s2p, s3p};
    const float* src = srcs[l];
    const int HW = c_hw[l];
    const int start = c_starts[l];
    const int b  = blockIdx.z;
    const int d0 = blockIdx.y * 64;
    const int s0 = ls * 64;
    const int t  = threadIdx.x;
    const float* sp = src + ((size_t)b * DD + d0) * (size_t)HW + s0;
#pragma unroll
    for (int i = 0; i < 16; ++i) {
        int lin = i * 256 + t;
        int dl = lin >> 6, sl = lin & 63;
        tile[sl][dl] = sp[(size_t)dl * HW + sl];
    }
    __syncthreads();
    ushort* dp = dst + ((size_t)b * SS + start + s0) * DD + d0;
#pragma unroll
    for (int i = 0; i < 16; ++i) {
        int lin = i * 256 + t;
        int sl = lin >> 6, dl = lin & 63;
        dp[(size_t)sl * DD + dl] = f2b(tile[sl][dl]);
    }
}

// ------------------------------------------------------------------
// all weights f32 -> bf16 in one dispatch
// ------------------------------------------------------------------
__global__ __launch_bounds__(256) void cvt_all_kernel(
    const float* __restrict__ so, const float* __restrict__ aw,
    const float* __restrict__ vp, const float* __restrict__ op,
    const float* __restrict__ l1, const float* __restrict__ l2,
    ushort* __restrict__ qso, ushort* __restrict__ qaw,
    ushort* __restrict__ qvp, ushort* __restrict__ qop,
    ushort* __restrict__ ql1, ushort* __restrict__ ql2)
{
    int i = blockIdx.x * 256 + threadIdx.x;
    const float* in; ushort* out; int j;
    if (i < 98304)       { in = so; out = qso; j = i; }
    else if (i < 147456) { in = aw; out = qaw; j = i - 98304; }
    else if (i < 245760) { in = vp; out = qvp; j = i - 147456; }
    else if (i < 344064) { in = op; out = qop; j = i - 245760; }
    else if (i < 737280) { in = l1; out = ql1; j = i - 344064; }
    else                 { in = l2; out = ql2; j = i - 737280; }
    float4 x = ((const float4*)in)[j];
    uint2 pk;
    pk.x = (unsigned)f2b(x.x) | ((unsigned)f2b(x.y) << 16);
    pk.y = (unsigned)f2b(x.z) | ((unsigned)f2b(x.w) << 16);
    ((uint2*)out)[j] = pk;
}

// q = bf16(qf + q_pos)
__global__ __launch_bounds__(256) void add_bf_kernel(
    const float* __restrict__ a, const float* __restrict__ b,
    ushort* __restrict__ o, int n4)
{
    int i = blockIdx.x * 256 + threadIdx.x;
    if (i < n4) {
        float4 x = ((const float4*)a)[i];
        float4 y = ((const float4*)b)[i];
        uint2 pk;
        pk.x = (unsigned)f2b(x.x + y.x) | ((unsigned)f2b(x.y + y.y) << 16);
        pk.y = (unsigned)f2b(x.z + y.z) | ((unsigned)f2b(x.w + y.w) << 16);
        ((uint2*)o)[i] = pk;
    }
}

// ------------------------------------------------------------------
// v-projection for ALL 6 layers. Block: 32 rows x 128 e; A panel (32x256,
// 16KB) staged once; z-loop stages only W k-tiles. Output is PLAIN ROW-MAJOR
// (z, B*S, 256) bf16 via LDS repack -> fully coalesced 32B/lane stores.
// ------------------------------------------------------------------
__global__ __launch_bounds__(256) void vp_gemm_kernel(
    const ushort* __restrict__ A, const ushort* __restrict__ W,
    const float* __restrict__ bias, ushort* __restrict__ out)
{
    __shared__ ushort As[32 * 256];   // 16 KB, swizzled A panel
    __shared__ ushort Ws[128 * 64];   // 16 KB, W k-tile; reused as repack buf
    const int tid  = threadIdx.x;
    const int wave = tid >> 6, lane = tid & 63;
    const size_t r0 = (size_t)blockIdx.x * 32;
    const int e0 = blockIdx.y * 128;
    const int wrow = wave >> 1, wcol = wave & 1;

    // stage A panel once: LDS(row, cs) holds global chunk cs^(row&7)
#pragma unroll
    for (int i = 0; i < 4; ++i) {
        int lin = i * 256 + tid;
        int row = lin >> 5;
        int cs  = lin & 31;
        int sc  = cs ^ (row & 7);
        __builtin_amdgcn_global_load_lds(
            (const __attribute__((address_space(1))) void*)(A + (r0 + row) * 256 + sc * 8),
            (__attribute__((address_space(3))) void*)(As + (size_t)lin * 8),
            16, 0, 0);
    }

    const int rlo  = lane & 15;
    const int lrow = (lane >> 4) << 2;
    const int lcol = lane & 15;

    for (int z = 0; z < NL; ++z) {
        const ushort* Wz = W + (size_t)z * 256 * 256;
        v4f acc[4];
#pragma unroll
        for (int n = 0; n < 4; ++n)
#pragma unroll
            for (int j = 0; j < 4; ++j) acc[n][j] = 0.f;

        for (int k0 = 0; k0 < 256; k0 += 64) {
#pragma unroll
            for (int i = 0; i < 4; ++i) {
                int lin = i * 256 + tid;
                int wr = lin >> 3;                 // 0..127 (e row)
                int wc = lin & 7;
                int sc = wc ^ (wr & 7);
                __builtin_amdgcn_global_load_lds(
                    (const __attribute__((address_space(1))) void*)(
                        Wz + (size_t)(e0 + wr) * 256 + k0 + sc * 8),
                    (__attribute__((address_space(3))) void*)(Ws + (size_t)lin * 8),
                    16, 0, 0);
            }
            __syncthreads();
#pragma unroll
            for (int ks = 0; ks < 2; ++ks) {
                const int chiA = (k0 >> 3) + ks * 4 + (lane >> 4);
                const int chiW = ks * 4 + (lane >> 4);
                const int ra = wrow * 16 + rlo;
                v8s af = *(const v8s*)((const char*)As + ra * 512 + ((chiA ^ (ra & 7)) << 4));
                v8s bf[4];
#pragma unroll
                for (int n = 0; n < 4; ++n) {
                    int r = wcol * 64 + n * 16 + rlo;
                    bf[n] = *(const v8s*)((const char*)Ws + r * 128 + ((chiW ^ (r & 7)) << 4));
                }
#pragma unroll
                for (int n = 0; n < 4; ++n)
                    acc[n] = __builtin_amdgcn_mfma_f32_16x16x32_bf16(af, bf[n], acc[n], 0, 0, 0);
            }
            __syncthreads();
        }

        // repack into LDS (272B row stride to spread banks), then coalesced store
        ushort* rp = Ws;  // 32 rows x 136 ushorts = 8.5 KB <= 16 KB
#pragma unroll
        for (int n = 0; n < 4; ++n) {
            const int ecol = wcol * 64 + n * 16 + lcol;
            const float bv = bias[z * 256 + e0 + ecol];
#pragma unroll
            for (int j = 0; j < 4; ++j) {
                const int rs = wrow * 16 + lrow + j;
                rp[rs * 136 + ecol] = f2b(acc[n][j] + bv);
            }
        }
        __syncthreads();
        {
            const int row = tid >> 3;
            const int seg = tid & 7;
            const ushort* s = rp + row * 136 + seg * 16;
            uint4 d0 = *(const uint4*)(s);
            uint4 d1 = *(const uint4*)(s + 8);
            ushort* o = out + (size_t)z * BB * SS * 256 + (r0 + row) * 256 + e0 + seg * 16;
            *(uint4*)(o) = d0;
            *(uint4*)(o + 8) = d1;
        }
        __syncthreads();   // protect rp/Ws before next z's staging
    }
}

// ------------------------------------------------------------------
// bf16 MFMA NT GEMM (generic): out[r,e] = sum_k A[r,k]*W[e,k] + bias[e]
// Tile (MF*32) x 128, BK=64. Used for q-proj (EPI_QF) and FFN-l1 (RELUB).
// ------------------------------------------------------------------
enum { EPI_RELUB = 1, EPI_QF = 4 };

template <int K, int EPI, int MF>
__global__ __launch_bounds__(256) void gemm_bf16(
    const ushort* __restrict__ A, const ushort* __restrict__ W,
    const float* __restrict__ bias, void* __restrict__ out, int E,
    const ushort* __restrict__ W2, const float* __restrict__ bias2,
    void* __restrict__ out2)
{
    __shared__ ushort As[MF * 32 * 64];
    __shared__ ushort Ws[128 * 64];
    const int tid  = threadIdx.x;
    const int wave = tid >> 6, lane = tid & 63;
    const size_t r0 = (size_t)blockIdx.x * (MF * 32);
    const int e0 = blockIdx.y * 128;
    const int wrow = wave >> 1, wcol = wave & 1;

    const ushort* Wbase = W;
    const float*  bbase = bias;
    int eoff = 0;
    if (EPI == EPI_QF && blockIdx.y == 2) {
        Wbase = W2; bbase = bias2; eoff = 256;
    }

    v4f acc[MF][4];
#pragma unroll
    for (int m = 0; m < MF; ++m)
#pragma unroll
        for (int n = 0; n < 4; ++n)
#pragma unroll
            for (int j = 0; j < 4; ++j) acc[m][n][j] = 0.f;

    const int srow   = lane >> 3;
    const int schunk = (lane & 7) ^ (srow & 7);
    const ushort* Ag = A + (r0 + wave * 8 + srow) * K + schunk * 8;
    const ushort* Wg = Wbase + ((size_t)(e0 - eoff + wave * 8 + srow)) * K + schunk * 8;

    for (int k0 = 0; k0 < K; k0 += 64) {
#pragma unroll
        for (int i = 0; i < MF; ++i) {
            __builtin_amdgcn_global_load_lds(
                (const __attribute__((address_space(1))) void*)(Ag + (size_t)(i * 32) * K + k0),
                (__attribute__((address_space(3))) void*)(As + (i * 32 + wave * 8) * 64),
                16, 0, 0);
        }
#pragma unroll
        for (int i = 0; i < 4; ++i) {
            __builtin_amdgcn_global_load_lds(
                (const __attribute__((address_space(1))) void*)(Wg + (size_t)(i * 32) * K + k0),
                (__attribute__((address_space(3))) void*)(Ws + (i * 32 + wave * 8) * 64),
                16, 0, 0);
        }
        __syncthreads();

        const int rlo = lane & 15;
#pragma unroll
        for (int ks = 0; ks < 2; ++ks) {
            const int chi = ks * 4 + (lane >> 4);
            v8s af[MF], bf[4];
#pragma unroll
            for (int m = 0; m < MF; ++m) {
                int r = wrow * (MF * 16) + m * 16 + rlo;
                af[m] = *(const v8s*)((const char*)As + r * 128 + ((chi ^ (r & 7)) << 4));
            }
#pragma unroll
            for (int n = 0; n < 4; ++n) {
                int r = wcol * 64 + n * 16 + rlo;
                bf[n] = *(const v8s*)((const char*)Ws + r * 128 + ((chi ^ (r & 7)) << 4));
            }
#pragma unroll
            for (int m = 0; m < MF; ++m)
#pragma unroll
                for (int n = 0; n < 4; ++n)
                    acc[m][n] = __builtin_amdgcn_mfma_f32_16x16x32_bf16(
                        af[m], bf[n], acc[m][n], 0, 0, 0);
        }
        __syncthreads();
    }

    const int lrow = (lane >> 4) << 2;
    const int lcol = lane & 15;
#pragma unroll
    for (int m = 0; m < MF; ++m) {
#pragma unroll
        for (int n = 0; n < 4; ++n) {
            const int ecol = e0 + wcol * 64 + n * 16 + lcol;
            const float bv = bbase[ecol - eoff];
#pragma unroll
            for (int j = 0; j < 4; ++j) {
                const size_t row = r0 + wrow * (MF * 16) + m * 16 + lrow + j;
                float val = acc[m][n][j] + bv;
                if (EPI == EPI_RELUB) {
                    ((ushort*)out)[row * E + ecol] = f2b(fmaxf(val, 0.f));
                } else {  // EPI_QF
                    if (eoff == 0) ((float*)out)[row * 256 + ecol] = val;
                    else           ((float*)out2)[row * 128 + (ecol - 256)] = val;
                }
            }
        }
    }
}

// ------------------------------------------------------------------
// GEMM (8192 x 256) + residual + LayerNorm fused epilogue.
// Block = 32 rows x 256 cols (full row -> block-local LN stats).
// ------------------------------------------------------------------
template <int K, bool ADDPOS>
__global__ __launch_bounds__(256) void gemm_ln_kernel(
    const ushort* __restrict__ A, const ushort* __restrict__ W,
    const float* __restrict__ bias, const float* __restrict__ res,
    const float* __restrict__ g, const float* __restrict__ beta,
    float* __restrict__ outF, ushort* __restrict__ outB,
    const float* __restrict__ pos)
{
    __shared__ ushort As[32 * 64];    // 4 KB
    __shared__ ushort Ws[256 * 64];   // 32 KB
    __shared__ float rsum[2][32], rsq[2][32];
    const int tid  = threadIdx.x;
    const int wave = tid >> 6, lane = tid & 63;
    const size_t r0 = (size_t)blockIdx.x * 32;
    const int wrow = wave >> 1, wcol = wave & 1;
    const int rlo = lane & 15;

    v4f acc[8];
#pragma unroll
    for (int n = 0; n < 8; ++n)
#pragma unroll
        for (int j = 0; j < 4; ++j) acc[n][j] = 0.f;

    const int arow = tid >> 3;
    const int asc  = (tid & 7) ^ (arow & 7);

    for (int k0 = 0; k0 < K; k0 += 64) {
        __builtin_amdgcn_global_load_lds(
            (const __attribute__((address_space(1))) void*)(A + (r0 + arow) * K + k0 + asc * 8),
            (__attribute__((address_space(3))) void*)(As + (size_t)tid * 8),
            16, 0, 0);
#pragma unroll
        for (int i = 0; i < 8; ++i) {
            int lin = i * 256 + tid;
            int wr = lin >> 3;
            int wsc = (lin & 7) ^ (wr & 7);
            __builtin_amdgcn_global_load_lds(
                (const __attribute__((address_space(1))) void*)(W + (size_t)wr * K + k0 + wsc * 8),
                (__attribute__((address_space(3))) void*)(Ws + (size_t)lin * 8),
                16, 0, 0);
        }
        __syncthreads();
#pragma unroll
        for (int ks = 0; ks < 2; ++ks) {
            const int chi = ks * 4 + (lane >> 4);
            const int ra = wrow * 16 + rlo;
            v8s af = *(const v8s*)((const char*)As + ra * 128 + ((chi ^ (ra & 7)) << 4));
            v8s bf[8];
#pragma unroll
            for (int n = 0; n < 8; ++n) {
                int rb = wcol * 128 + n * 16 + rlo;
                bf[n] = *(const v8s*)((const char*)Ws + rb * 128 + ((chi ^ (rb & 7)) << 4));
            }
#pragma unroll
            for (int n = 0; n < 8; ++n)
                acc[n] = __builtin_amdgcn_mfma_f32_16x16x32_bf16(af, bf[n], acc[n], 0, 0, 0);
        }
        __syncthreads();
    }

    const int lrow = (lane >> 4) << 2;
    const int lcol = lane & 15;
    float sums[4] = {0.f, 0.f, 0.f, 0.f};
    float sqs[4]  = {0.f, 0.f, 0.f, 0.f};
#pragma unroll
    for (int n = 0; n < 8; ++n) {
        const int ecol = wcol * 128 + n * 16 + lcol;
        const float bv = bias[ecol];
#pragma unroll
        for (int j = 0; j < 4; ++j) {
            const size_t row = r0 + wrow * 16 + lrow + j;
            float v = acc[n][j] + bv + res[row * 256 + ecol];
            acc[n][j] = v;
            sums[j] += v;
            sqs[j]  += v * v;
        }
    }
#pragma unroll
    for (int off = 1; off < 16; off <<= 1) {
#pragma unroll
        for (int j = 0; j < 4; ++j) {
            sums[j] += __shfl_xor(sums[j], off);
            sqs[j]  += __shfl_xor(sqs[j], off);
        }
    }
    if ((lane & 15) == 0) {
#pragma unroll
        for (int j = 0; j < 4; ++j) {
            int ridx = wrow * 16 + lrow + j;
            rsum[wcol][ridx] = sums[j];
            rsq[wcol][ridx]  = sqs[j];
        }
    }
    __syncthreads();
#pragma unroll
    for (int j = 0; j < 4; ++j) {
        const int ridx = wrow * 16 + lrow + j;
        const float s  = rsum[0][ridx] + rsum[1][ridx];
        const float sq = rsq[0][ridx] + rsq[1][ridx];
        const float mean = s * (1.f / 256.f);
        const float var  = sq * (1.f / 256.f) - mean * mean;
        const float rstd = rsqrtf(var + 1e-5f);
        const size_t row = r0 + wrow * 16 + lrow + j;
#pragma unroll
        for (int n = 0; n < 8; ++n) {
            const int ecol = wcol * 128 + n * 16 + lcol;
            float o = (acc[n][j] - mean) * rstd * g[ecol] + beta[ecol];
            outF[row * 256 + ecol] = o;
            float ob = ADDPOS ? (o + pos[row * 256 + ecol]) : o;
            outB[row * 256 + ecol] = f2b(ob);
        }
    }
}

// ------------------------------------------------------------------
// MSDA sampling + aggregation, wave64 per (b,q) covering all 8 heads.
// v layout: (B, S, 256) row-major bf16 (per layer).
// ------------------------------------------------------------------
__global__ __launch_bounds__(256) void msda_kernel(
    const ushort* __restrict__ v, const float* __restrict__ offs,
    const float* __restrict__ awb, const float* __restrict__ qref,
    ushort* __restrict__ out)
{
    __shared__ uint2 iw[4][128][4];
    const int wid  = threadIdx.x >> 6;
    const int lane = threadIdx.x & 63;
    const int gid  = blockIdx.x * 4 + wid;     // (b,q)
    const int q = gid & (NQ - 1);
    const int b = gid >> 12;
    const size_t bq = (size_t)b * NQ + q;

    const float rx = qref[bq * 2 + 0];
    const float ry = qref[bq * 2 + 1];

#pragma unroll
    for (int it = 0; it < 2; ++it) {
        const int t = it * 64 + lane;          // task: h = t>>4, p = t&15
        const int pp = t & 15;
        const int lvl = pp >> 2;
        float a_raw = awb[bq * 128 + t];
        float mx = a_raw;
        mx = fmaxf(mx, __shfl_xor(mx, 1));
        mx = fmaxf(mx, __shfl_xor(mx, 2));
        mx = fmaxf(mx, __shfl_xor(mx, 4));
        mx = fmaxf(mx, __shfl_xor(mx, 8));
        float e = expf(a_raw - mx);
        float sum = e;
        sum += __shfl_xor(sum, 1);
        sum += __shfl_xor(sum, 2);
        sum += __shfl_xor(sum, 4);
        sum += __shfl_xor(sum, 8);
        const float a = e / sum;

        float2 oxy = *(const float2*)(offs + bq * 256 + t * 2);
        const int Wl = c_dims[lvl];
        const int st = c_starts[lvl];
        const float fW = (float)Wl;
        float x = fmaf(rx, fW, oxy.x) - 0.5f;
        float y = fmaf(ry, fW, oxy.y) - 0.5f;
        float x0f = floorf(x), y0f = floorf(y);
        float wx = x - x0f, wy = y - y0f;
        int x0 = (int)x0f, y0 = (int)y0f;
        const unsigned hoff = (unsigned)((t >> 4) * 64);   // h*DH*2 bytes
#pragma unroll
        for (int c = 0; c < 4; ++c) {
            int dx = c & 1, dy = c >> 1;
            int xc = x0 + dx, yc = y0 + dy;
            bool valid = (xc >= 0) & (xc < Wl) & (yc >= 0) & (yc < Wl);
            int xi = min(max(xc, 0), Wl - 1);
            int yi = min(max(yc, 0), Wl - 1);
            float w = (dx ? wx : 1.f - wx) * (dy ? wy : 1.f - wy);
            uint2 tt;
            tt.x = (unsigned)((st + yi * Wl + xi) * 512) + hoff;   // byte off in (S,256)
            tt.y = __float_as_uint(valid ? a * w : 0.f);
            iw[wid][t][c] = tt;
        }
    }
    __syncthreads();

    const int c   = lane >> 4;
    const int dh2 = lane & 15;
    const char* vbase = (const char*)(v + (size_t)b * SS * 256) + dh2 * 4;
#pragma unroll
    for (int h = 0; h < NH; ++h) {
        float acc0 = 0.f, acc1 = 0.f;
#pragma unroll
        for (int p = 0; p < 16; ++p) {
            uint2 t = iw[wid][h * 16 + p][c];
            float cw = __uint_as_float(t.y);
            unsigned v2 = *(const unsigned*)(vbase + t.x);
            float lo = __uint_as_float(v2 << 16);
            float hi = __uint_as_float(v2 & 0xffff0000u);
            acc0 = fmaf(cw, lo, acc0);
            acc1 = fmaf(cw, hi, acc1);
        }
        acc0 += __shfl_xor(acc0, 16); acc0 += __shfl_xor(acc0, 32);
        acc1 += __shfl_xor(acc1, 16); acc1 += __shfl_xor(acc1, 32);
        if (lane < 16) {
            unsigned pk = (unsigned)f2b(acc0) | ((unsigned)f2b(acc1) << 16);
            *(unsigned*)(out + bq * DD + h * DH + dh2 * 2) = pk;
        }
    }
}

// ------------------------------------------------------------------
extern "C" void kernel_launch(void* const* d_in, const int* in_sizes, int n_in,
                              void* d_out, int out_size, void* d_ws, size_t ws_size,
                              hipStream_t stream)
{
    const float* src[4]  = {(const float*)d_in[0], (const float*)d_in[3],
                            (const float*)d_in[6], (const float*)d_in[9]};
    const float* q_feat  = (const float*)d_in[12];
    const float* q_pos   = (const float*)d_in[13];
    const float* q_ref   = (const float*)d_in[14];
    const float* so_w = (const float*)d_in[16];
    const float* so_b = (const float*)d_in[17];
    const float* aw_w = (const float*)d_in[18];
    const float* aw_b = (const float*)d_in[19];
    const float* vp_w = (const float*)d_in[20];
    const float* vp_b = (const float*)d_in[21];
    const float* op_w = (const float*)d_in[22];
    const float* op_b = (const float*)d_in[23];
    const float* n1_g = (const float*)d_in[24];
    const float* n1_b = (const float*)d_in[25];
    const float* l1_w = (const float*)d_in[26];
    const float* l1_b = (const float*)d_in[27];
    const float* l2_w = (const float*)d_in[28];
    const float* l2_b = (const float*)d_in[29];
    const float* n2_g = (const float*)d_in[30];
    const float* n2_b = (const float*)d_in[31];

    char* p = (char*)d_ws;
    auto alloc = [&](size_t bytes) { char* r = p; p += (bytes + 255) & ~255ULL; return r; };

    ushort* src_flat = (ushort*)alloc((size_t)BB * SS * DD * 2);
    ushort* v_buf6   = (ushort*)alloc((size_t)NL * BB * SS * DD * 2);
    ushort* q_bf     = (ushort*)alloc((size_t)BB * NQ * DD * 2);
    float*  offs     = (float*) alloc((size_t)BB * NQ * 256 * 4);
    float*  awb      = (float*) alloc((size_t)BB * NQ * 128 * 4);
    ushort* msda_bf  = (ushort*)alloc((size_t)BB * NQ * DD * 2);
    ushort* hbuf     = (ushort*)alloc((size_t)BB * NQ * DFF * 2);
    ushort* qf_bf    = (ushort*)alloc((size_t)BB * NQ * DD * 2);
    ushort* w_so     = (ushort*)alloc((size_t)NL * 256 * 256 * 2);
    ushort* w_aw     = (ushort*)alloc((size_t)NL * 128 * 256 * 2);
    ushort* w_vp     = (ushort*)alloc((size_t)NL * 256 * 256 * 2);
    ushort* w_op     = (ushort*)alloc((size_t)NL * 256 * 256 * 2);
    ushort* w_l1     = (ushort*)alloc((size_t)NL * DFF * 256 * 2);
    ushort* w_l2     = (ushort*)alloc((size_t)NL * 256 * DFF * 2);

    float* qf = (float*)d_out;   // residual stream lives in d_out

    cvt_all_kernel<<<4416, 256, 0, stream>>>(
        so_w, aw_w, vp_w, op_w, l1_w, l2_w,
        w_so, w_aw, w_vp, w_op, w_l1, w_l2);

    flatten_all_kernel<<<dim3(340, 4, 2), 256, 0, stream>>>(
        src[0], src[1], src[2], src[3], src_flat);

    const int RQ = BB * NQ;       // 8192 query rows
    const int RV = BB * SS;       // 43520 value rows

    // q_bf for layer 0: bf16(q_feat + q_pos)
    add_bf_kernel<<<RQ * DD / (256 * 4), 256, 0, stream>>>(q_feat, q_pos, q_bf, RQ * DD / 4);

    // all 6 layers' v-projections, A-panel staged once, coalesced row-major out
    vp_gemm_kernel<<<dim3(RV / 32, 2), 256, 0, stream>>>(
        src_flat, w_vp, vp_b, v_buf6);

    for (int l = 0; l < NL; ++l) {
        // fused q-projections: offsets (E 0..255) + attention logits (256..383)
        gemm_bf16<256, EPI_QF, 2><<<dim3(RQ / 64, 3), 256, 0, stream>>>(
            q_bf, w_so + (size_t)l * 256 * 256, so_b + (size_t)l * 256, offs, 256,
            w_aw + (size_t)l * 128 * 256, aw_b + (size_t)l * 128, awb);

        // bilinear sampling + weighted aggregation -> msda_bf (B,NQ,D)
        msda_kernel<<<(BB * NQ) / 4, 256, 0, stream>>>(
            v_buf6 + (size_t)l * BB * SS * DD, offs, awb, q_ref, msda_bf);

        // output projection + residual + LN1 (writes qf f32, qf_bf bf16)
        gemm_ln_kernel<256, false><<<RQ / 32, 256, 0, stream>>>(
            msda_bf, w_op + (size_t)l * 256 * 256, op_b + (size_t)l * 256,
            (l == 0 ? q_feat : qf), n1_g + l * 256, n1_b + l * 256,
            qf, qf_bf, nullptr);

        // FFN up + ReLU
        gemm_bf16<256, EPI_RELUB, 4><<<dim3(RQ / 128, DFF / 128), 256, 0, stream>>>(
            qf_bf, w_l1 + (size_t)l * DFF * 256, l1_b + (size_t)l * DFF, hbuf, DFF,
            nullptr, nullptr, nullptr);

        // FFN down + residual + LN2 (writes qf f32; q_bf = bf16(out + q_pos))
        gemm_ln_kernel<1024, true><<<RQ / 32, 256, 0, stream>>>(
            hbuf, w_l2 + (size_t)l * 256 * DFF, l2_b + (size_t)l * 256,
            qf, n2_g + l * 256, n2_b + l * 256,
            qf, q_bf, q_pos);
    }

    (void)in_sizes; (void)n_in; (void)out_size; (void)ws_size;
}

// Round 11
// 511.583 us; speedup vs baseline: 1.0980x; 1.0980x over previous
//
#include <hip/hip_runtime.h>
#include <math.h>

// ---- problem constants ----
#define BB 2
#define DD 256
#define NH 8
#define DH 32
#define NPNP 4
#define LV 4
#define NQ 4096
#define NL 6
#define DFF 1024
#define SS 21760   // 128*128 + 64*64 + 32*32 + 16*16

typedef short v8s __attribute__((ext_vector_type(8)));
typedef float v4f __attribute__((ext_vector_type(4)));

__device__ __forceinline__ ushort f2b(float f) {
    union { float f; unsigned u; } v; v.f = f;
    unsigned r = v.u + 0x7fffu + ((v.u >> 16) & 1u);
    return (ushort)(r >> 16);
}

__device__ __constant__ int c_dims[4]   = {128, 64, 32, 16};
__device__ __constant__ int c_starts[4] = {0, 16384, 20480, 21504};
__device__ __constant__ int c_hw[4]     = {16384, 4096, 1024, 256};

// ------------------------------------------------------------------
// flatten all 4 levels: src_l (B, D, H, W) f32 -> src_flat (B, S, D) bf16
// ------------------------------------------------------------------
__global__ __launch_bounds__(256) void flatten_all_kernel(
    const float* __restrict__ s0p, const float* __restrict__ s1p,
    const float* __restrict__ s2p, const float* __restrict__ s3p,
    ushort* __restrict__ dst)
{
    __shared__ float tile[64][65];
    int bx = blockIdx.x;
    int l, ls;
    if (bx < 256)      { l = 0; ls = bx; }
    else if (bx < 320) { l = 1; ls = bx - 256; }
    else if (bx < 336) { l = 2; ls = bx - 320; }
    else               { l = 3; ls = bx - 336; }
    const float* srcs[4] = {s0p, s1p, s2p, s3p};
    const float* src = srcs[l];
    const int HW = c_hw[l];
    const int start = c_starts[l];
    const int b  = blockIdx.z;
    const int d0 = blockIdx.y * 64;
    const int s0 = ls * 64;
    const int t  = threadIdx.x;
    const float* sp = src + ((size_t)b * DD + d0) * (size_t)HW + s0;
#pragma unroll
    for (int i = 0; i < 16; ++i) {
        int lin = i * 256 + t;
        int dl = lin >> 6, sl = lin & 63;
        tile[sl][dl] = sp[(size_t)dl * HW + sl];
    }
    __syncthreads();
    ushort* dp = dst + ((size_t)b * SS + start + s0) * DD + d0;
#pragma unroll
    for (int i = 0; i < 16; ++i) {
        int lin = i * 256 + t;
        int sl = lin >> 6, dl = lin & 63;
        dp[(size_t)sl * DD + dl] = f2b(tile[sl][dl]);
    }
}

// ------------------------------------------------------------------
// all weights f32 -> bf16 in one dispatch
// ------------------------------------------------------------------
__global__ __launch_bounds__(256) void cvt_all_kernel(
    const float* __restrict__ so, const float* __restrict__ aw,
    const float* __restrict__ vp, const float* __restrict__ op,
    const float* __restrict__ l1, const float* __restrict__ l2,
    ushort* __restrict__ qso, ushort* __restrict__ qaw,
    ushort* __restrict__ qvp, ushort* __restrict__ qop,
    ushort* __restrict__ ql1, ushort* __restrict__ ql2)
{
    int i = blockIdx.x * 256 + threadIdx.x;
    const float* in; ushort* out; int j;
    if (i < 98304)       { in = so; out = qso; j = i; }
    else if (i < 147456) { in = aw; out = qaw; j = i - 98304; }
    else if (i < 245760) { in = vp; out = qvp; j = i - 147456; }
    else if (i < 344064) { in = op; out = qop; j = i - 245760; }
    else if (i < 737280) { in = l1; out = ql1; j = i - 344064; }
    else                 { in = l2; out = ql2; j = i - 737280; }
    float4 x = ((const float4*)in)[j];
    uint2 pk;
    pk.x = (unsigned)f2b(x.x) | ((unsigned)f2b(x.y) << 16);
    pk.y = (unsigned)f2b(x.z) | ((unsigned)f2b(x.w) << 16);
    ((uint2*)out)[j] = pk;
}

// q = bf16(qf + q_pos)
__global__ __launch_bounds__(256) void add_bf_kernel(
    const float* __restrict__ a, const float* __restrict__ b,
    ushort* __restrict__ o, int n4)
{
    int i = blockIdx.x * 256 + threadIdx.x;
    if (i < n4) {
        float4 x = ((const float4*)a)[i];
        float4 y = ((const float4*)b)[i];
        uint2 pk;
        pk.x = (unsigned)f2b(x.x + y.x) | ((unsigned)f2b(x.y + y.y) << 16);
        pk.y = (unsigned)f2b(x.z + y.z) | ((unsigned)f2b(x.w + y.w) << 16);
        ((uint2*)o)[i] = pk;
    }
}

// ------------------------------------------------------------------
// v-projection, z (layer) in grid. 128x128 tile, BK=64, 4 waves (2x2),
// wave 64x64 (16 MFMA per k-half). Epilogue repacks fragments through LDS
// and stores PLAIN ROW-MAJOR (z, B*S, 256) bf16 with coalesced 256B rows.
// ------------------------------------------------------------------
__global__ __launch_bounds__(256) void vp_gemm_kernel(
    const ushort* __restrict__ A, const ushort* __restrict__ W,
    const float* __restrict__ bias, ushort* __restrict__ out)
{
    __shared__ ushort As[128 * 64];     // 16 KB
    __shared__ ushort Ws[128 * 64];     // 16 KB
    __shared__ ushort rp[128 * 136];    // 34 KB repack buffer
    const int tid  = threadIdx.x;
    const int wave = tid >> 6, lane = tid & 63;
    const size_t r0 = (size_t)blockIdx.x * 128;
    const int e0 = blockIdx.y * 128;
    const int z  = blockIdx.z;
    const int wrow = wave >> 1, wcol = wave & 1;
    const ushort* Wz = W + (size_t)z * 256 * 256;

    v4f acc[4][4];
#pragma unroll
    for (int m = 0; m < 4; ++m)
#pragma unroll
        for (int n = 0; n < 4; ++n)
#pragma unroll
            for (int j = 0; j < 4; ++j) acc[m][n][j] = 0.f;

    const int srow   = lane >> 3;
    const int schunk = (lane & 7) ^ (srow & 7);
    const ushort* Ag = A + (r0 + wave * 8 + srow) * 256 + schunk * 8;
    const ushort* Wg = Wz + ((size_t)(e0 + wave * 8 + srow)) * 256 + schunk * 8;

    for (int k0 = 0; k0 < 256; k0 += 64) {
#pragma unroll
        for (int i = 0; i < 4; ++i) {
            __builtin_amdgcn_global_load_lds(
                (const __attribute__((address_space(1))) void*)(Ag + (size_t)(i * 32) * 256 + k0),
                (__attribute__((address_space(3))) void*)(As + (i * 32 + wave * 8) * 64),
                16, 0, 0);
            __builtin_amdgcn_global_load_lds(
                (const __attribute__((address_space(1))) void*)(Wg + (size_t)(i * 32) * 256 + k0),
                (__attribute__((address_space(3))) void*)(Ws + (i * 32 + wave * 8) * 64),
                16, 0, 0);
        }
        __syncthreads();

        const int rlo = lane & 15;
#pragma unroll
        for (int ks = 0; ks < 2; ++ks) {
            const int chi = ks * 4 + (lane >> 4);
            v8s af[4], bf[4];
#pragma unroll
            for (int m = 0; m < 4; ++m) {
                int r = wrow * 64 + m * 16 + rlo;
                af[m] = *(const v8s*)((const char*)As + r * 128 + ((chi ^ (r & 7)) << 4));
            }
#pragma unroll
            for (int n = 0; n < 4; ++n) {
                int r = wcol * 64 + n * 16 + rlo;
                bf[n] = *(const v8s*)((const char*)Ws + r * 128 + ((chi ^ (r & 7)) << 4));
            }
#pragma unroll
            for (int m = 0; m < 4; ++m)
#pragma unroll
                for (int n = 0; n < 4; ++n)
                    acc[m][n] = __builtin_amdgcn_mfma_f32_16x16x32_bf16(
                        af[m], bf[n], acc[m][n], 0, 0, 0);
        }
        __syncthreads();
    }

    // repack fragments -> rp (136-ushort row stride), then coalesced stores
    const int lrow = (lane >> 4) << 2;
    const int lcol = lane & 15;
#pragma unroll
    for (int m = 0; m < 4; ++m) {
#pragma unroll
        for (int n = 0; n < 4; ++n) {
            const int ecol = wcol * 64 + n * 16 + lcol;
            const float bv = bias[z * 256 + e0 + ecol];
#pragma unroll
            for (int j = 0; j < 4; ++j) {
                const int rs = wrow * 64 + m * 16 + lrow + j;
                rp[rs * 136 + ecol] = f2b(acc[m][n][j] + bv);
            }
        }
    }
    __syncthreads();
    {
        ushort* oz = out + (size_t)z * BB * SS * 256;
        const int seg = tid & 15;             // 16 segs x 16B = 256B row part
#pragma unroll
        for (int i = 0; i < 8; ++i) {
            const int row = i * 16 + (tid >> 4);
            uint4 d = *(const uint4*)(rp + row * 136 + seg * 8);
            *(uint4*)(oz + (r0 + row) * 256 + e0 + seg * 8) = d;
        }
    }
}

// ------------------------------------------------------------------
// bf16 MFMA NT GEMM (generic): out[r,e] = sum_k A[r,k]*W[e,k] + bias[e]
// Tile (MF*32) x 128, BK=64. Used for q-proj (EPI_QF) and FFN-l1 (RELUB).
// ------------------------------------------------------------------
enum { EPI_RELUB = 1, EPI_QF = 4 };

template <int K, int EPI, int MF>
__global__ __launch_bounds__(256) void gemm_bf16(
    const ushort* __restrict__ A, const ushort* __restrict__ W,
    const float* __restrict__ bias, void* __restrict__ out, int E,
    const ushort* __restrict__ W2, const float* __restrict__ bias2,
    void* __restrict__ out2)
{
    __shared__ ushort As[MF * 32 * 64];
    __shared__ ushort Ws[128 * 64];
    const int tid  = threadIdx.x;
    const int wave = tid >> 6, lane = tid & 63;
    const size_t r0 = (size_t)blockIdx.x * (MF * 32);
    const int e0 = blockIdx.y * 128;
    const int wrow = wave >> 1, wcol = wave & 1;

    const ushort* Wbase = W;
    const float*  bbase = bias;
    int eoff = 0;
    if (EPI == EPI_QF && blockIdx.y == 2) {
        Wbase = W2; bbase = bias2; eoff = 256;
    }

    v4f acc[MF][4];
#pragma unroll
    for (int m = 0; m < MF; ++m)
#pragma unroll
        for (int n = 0; n < 4; ++n)
#pragma unroll
            for (int j = 0; j < 4; ++j) acc[m][n][j] = 0.f;

    const int srow   = lane >> 3;
    const int schunk = (lane & 7) ^ (srow & 7);
    const ushort* Ag = A + (r0 + wave * 8 + srow) * K + schunk * 8;
    const ushort* Wg = Wbase + ((size_t)(e0 - eoff + wave * 8 + srow)) * K + schunk * 8;

    for (int k0 = 0; k0 < K; k0 += 64) {
#pragma unroll
        for (int i = 0; i < MF; ++i) {
            __builtin_amdgcn_global_load_lds(
                (const __attribute__((address_space(1))) void*)(Ag + (size_t)(i * 32) * K + k0),
                (__attribute__((address_space(3))) void*)(As + (i * 32 + wave * 8) * 64),
                16, 0, 0);
        }
#pragma unroll
        for (int i = 0; i < 4; ++i) {
            __builtin_amdgcn_global_load_lds(
                (const __attribute__((address_space(1))) void*)(Wg + (size_t)(i * 32) * K + k0),
                (__attribute__((address_space(3))) void*)(Ws + (i * 32 + wave * 8) * 64),
                16, 0, 0);
        }
        __syncthreads();

        const int rlo = lane & 15;
#pragma unroll
        for (int ks = 0; ks < 2; ++ks) {
            const int chi = ks * 4 + (lane >> 4);
            v8s af[MF], bf[4];
#pragma unroll
            for (int m = 0; m < MF; ++m) {
                int r = wrow * (MF * 16) + m * 16 + rlo;
                af[m] = *(const v8s*)((const char*)As + r * 128 + ((chi ^ (r & 7)) << 4));
            }
#pragma unroll
            for (int n = 0; n < 4; ++n) {
                int r = wcol * 64 + n * 16 + rlo;
                bf[n] = *(const v8s*)((const char*)Ws + r * 128 + ((chi ^ (r & 7)) << 4));
            }
#pragma unroll
            for (int m = 0; m < MF; ++m)
#pragma unroll
                for (int n = 0; n < 4; ++n)
                    acc[m][n] = __builtin_amdgcn_mfma_f32_16x16x32_bf16(
                        af[m], bf[n], acc[m][n], 0, 0, 0);
        }
        __syncthreads();
    }

    const int lrow = (lane >> 4) << 2;
    const int lcol = lane & 15;
#pragma unroll
    for (int m = 0; m < MF; ++m) {
#pragma unroll
        for (int n = 0; n < 4; ++n) {
            const int ecol = e0 + wcol * 64 + n * 16 + lcol;
            const float bv = bbase[ecol - eoff];
#pragma unroll
            for (int j = 0; j < 4; ++j) {
                const size_t row = r0 + wrow * (MF * 16) + m * 16 + lrow + j;
                float val = acc[m][n][j] + bv;
                if (EPI == EPI_RELUB) {
                    ((ushort*)out)[row * E + ecol] = f2b(fmaxf(val, 0.f));
                } else {  // EPI_QF
                    if (eoff == 0) ((float*)out)[row * 256 + ecol] = val;
                    else           ((float*)out2)[row * 128 + (ecol - 256)] = val;
                }
            }
        }
    }
}

// ------------------------------------------------------------------
// GEMM (8192 x 256) + residual + LayerNorm fused epilogue.
// Block = 32 rows x 256 cols (full row -> block-local LN stats).
// ------------------------------------------------------------------
template <int K, bool ADDPOS>
__global__ __launch_bounds__(256) void gemm_ln_kernel(
    const ushort* __restrict__ A, const ushort* __restrict__ W,
    const float* __restrict__ bias, const float* __restrict__ res,
    const float* __restrict__ g, const float* __restrict__ beta,
    float* __restrict__ outF, ushort* __restrict__ outB,
    const float* __restrict__ pos)
{
    __shared__ ushort As[32 * 64];    // 4 KB
    __shared__ ushort Ws[256 * 64];   // 32 KB
    __shared__ float rsum[2][32], rsq[2][32];
    const int tid  = threadIdx.x;
    const int wave = tid >> 6, lane = tid & 63;
    const size_t r0 = (size_t)blockIdx.x * 32;
    const int wrow = wave >> 1, wcol = wave & 1;
    const int rlo = lane & 15;

    v4f acc[8];
#pragma unroll
    for (int n = 0; n < 8; ++n)
#pragma unroll
        for (int j = 0; j < 4; ++j) acc[n][j] = 0.f;

    const int arow = tid >> 3;
    const int asc  = (tid & 7) ^ (arow & 7);

    for (int k0 = 0; k0 < K; k0 += 64) {
        __builtin_amdgcn_global_load_lds(
            (const __attribute__((address_space(1))) void*)(A + (r0 + arow) * K + k0 + asc * 8),
            (__attribute__((address_space(3))) void*)(As + (size_t)tid * 8),
            16, 0, 0);
#pragma unroll
        for (int i = 0; i < 8; ++i) {
            int lin = i * 256 + tid;
            int wr = lin >> 3;
            int wsc = (lin & 7) ^ (wr & 7);
            __builtin_amdgcn_global_load_lds(
                (const __attribute__((address_space(1))) void*)(W + (size_t)wr * K + k0 + wsc * 8),
                (__attribute__((address_space(3))) void*)(Ws + (size_t)lin * 8),
                16, 0, 0);
        }
        __syncthreads();
#pragma unroll
        for (int ks = 0; ks < 2; ++ks) {
            const int chi = ks * 4 + (lane >> 4);
            const int ra = wrow * 16 + rlo;
            v8s af = *(const v8s*)((const char*)As + ra * 128 + ((chi ^ (ra & 7)) << 4));
            v8s bf[8];
#pragma unroll
            for (int n = 0; n < 8; ++n) {
                int rb = wcol * 128 + n * 16 + rlo;
                bf[n] = *(const v8s*)((const char*)Ws + rb * 128 + ((chi ^ (rb & 7)) << 4));
            }
#pragma unroll
            for (int n = 0; n < 8; ++n)
                acc[n] = __builtin_amdgcn_mfma_f32_16x16x32_bf16(af, bf[n], acc[n], 0, 0, 0);
        }
        __syncthreads();
    }

    const int lrow = (lane >> 4) << 2;
    const int lcol = lane & 15;
    float sums[4] = {0.f, 0.f, 0.f, 0.f};
    float sqs[4]  = {0.f, 0.f, 0.f, 0.f};
#pragma unroll
    for (int n = 0; n < 8; ++n) {
        const int ecol = wcol * 128 + n * 16 + lcol;
        const float bv = bias[ecol];
#pragma unroll
        for (int j = 0; j < 4; ++j) {
            const size_t row = r0 + wrow * 16 + lrow + j;
            float v = acc[n][j] + bv + res[row * 256 + ecol];
            acc[n][j] = v;
            sums[j] += v;
            sqs[j]  += v * v;
        }
    }
#pragma unroll
    for (int off = 1; off < 16; off <<= 1) {
#pragma unroll
        for (int j = 0; j < 4; ++j) {
            sums[j] += __shfl_xor(sums[j], off);
            sqs[j]  += __shfl_xor(sqs[j], off);
        }
    }
    if ((lane & 15) == 0) {
#pragma unroll
        for (int j = 0; j < 4; ++j) {
            int ridx = wrow * 16 + lrow + j;
            rsum[wcol][ridx] = sums[j];
            rsq[wcol][ridx]  = sqs[j];
        }
    }
    __syncthreads();
#pragma unroll
    for (int j = 0; j < 4; ++j) {
        const int ridx = wrow * 16 + lrow + j;
        const float s  = rsum[0][ridx] + rsum[1][ridx];
        const float sq = rsq[0][ridx] + rsq[1][ridx];
        const float mean = s * (1.f / 256.f);
        const float var  = sq * (1.f / 256.f) - mean * mean;
        const float rstd = rsqrtf(var + 1e-5f);
        const size_t row = r0 + wrow * 16 + lrow + j;
#pragma unroll
        for (int n = 0; n < 8; ++n) {
            const int ecol = wcol * 128 + n * 16 + lcol;
            float o = (acc[n][j] - mean) * rstd * g[ecol] + beta[ecol];
            outF[row * 256 + ecol] = o;
            float ob = ADDPOS ? (o + pos[row * 256 + ecol]) : o;
            outB[row * 256 + ecol] = f2b(ob);
        }
    }
}

// ------------------------------------------------------------------
// MSDA sampling + aggregation, wave64 per (b,q) covering all 8 heads.
// v layout: (B, S, 256) row-major bf16 (per layer).
// ------------------------------------------------------------------
__global__ __launch_bounds__(256) void msda_kernel(
    const ushort* __restrict__ v, const float* __restrict__ offs,
    const float* __restrict__ awb, const float* __restrict__ qref,
    ushort* __restrict__ out)
{
    __shared__ uint2 iw[4][128][4];
    const int wid  = threadIdx.x >> 6;
    const int lane = threadIdx.x & 63;
    const int gid  = blockIdx.x * 4 + wid;     // (b,q)
    const int q = gid & (NQ - 1);
    const int b = gid >> 12;
    const size_t bq = (size_t)b * NQ + q;

    const float rx = qref[bq * 2 + 0];
    const float ry = qref[bq * 2 + 1];

#pragma unroll
    for (int it = 0; it < 2; ++it) {
        const int t = it * 64 + lane;          // task: h = t>>4, p = t&15
        const int pp = t & 15;
        const int lvl = pp >> 2;
        float a_raw = awb[bq * 128 + t];
        float mx = a_raw;
        mx = fmaxf(mx, __shfl_xor(mx, 1));
        mx = fmaxf(mx, __shfl_xor(mx, 2));
        mx = fmaxf(mx, __shfl_xor(mx, 4));
        mx = fmaxf(mx, __shfl_xor(mx, 8));
        float e = expf(a_raw - mx);
        float sum = e;
        sum += __shfl_xor(sum, 1);
        sum += __shfl_xor(sum, 2);
        sum += __shfl_xor(sum, 4);
        sum += __shfl_xor(sum, 8);
        const float a = e / sum;

        float2 oxy = *(const float2*)(offs + bq * 256 + t * 2);
        const int Wl = c_dims[lvl];
        const int st = c_starts[lvl];
        const float fW = (float)Wl;
        float x = fmaf(rx, fW, oxy.x) - 0.5f;
        float y = fmaf(ry, fW, oxy.y) - 0.5f;
        float x0f = floorf(x), y0f = floorf(y);
        float wx = x - x0f, wy = y - y0f;
        int x0 = (int)x0f, y0 = (int)y0f;
        const unsigned hoff = (unsigned)((t >> 4) * 64);   // h*DH*2 bytes
#pragma unroll
        for (int c = 0; c < 4; ++c) {
            int dx = c & 1, dy = c >> 1;
            int xc = x0 + dx, yc = y0 + dy;
            bool valid = (xc >= 0) & (xc < Wl) & (yc >= 0) & (yc < Wl);
            int xi = min(max(xc, 0), Wl - 1);
            int yi = min(max(yc, 0), Wl - 1);
            float w = (dx ? wx : 1.f - wx) * (dy ? wy : 1.f - wy);
            uint2 tt;
            tt.x = (unsigned)((st + yi * Wl + xi) * 512) + hoff;   // byte off in (S,256)
            tt.y = __float_as_uint(valid ? a * w : 0.f);
            iw[wid][t][c] = tt;
        }
    }
    __syncthreads();

    const int c   = lane >> 4;
    const int dh2 = lane & 15;
    const char* vbase = (const char*)(v + (size_t)b * SS * 256) + dh2 * 4;
#pragma unroll
    for (int h = 0; h < NH; ++h) {
        float acc0 = 0.f, acc1 = 0.f;
#pragma unroll
        for (int p = 0; p < 16; ++p) {
            uint2 t = iw[wid][h * 16 + p][c];
            float cw = __uint_as_float(t.y);
            unsigned v2 = *(const unsigned*)(vbase + t.x);
            float lo = __uint_as_float(v2 << 16);
            float hi = __uint_as_float(v2 & 0xffff0000u);
            acc0 = fmaf(cw, lo, acc0);
            acc1 = fmaf(cw, hi, acc1);
        }
        acc0 += __shfl_xor(acc0, 16); acc0 += __shfl_xor(acc0, 32);
        acc1 += __shfl_xor(acc1, 16); acc1 += __shfl_xor(acc1, 32);
        if (lane < 16) {
            unsigned pk = (unsigned)f2b(acc0) | ((unsigned)f2b(acc1) << 16);
            *(unsigned*)(out + bq * DD + h * DH + dh2 * 2) = pk;
        }
    }
}

// ------------------------------------------------------------------
extern "C" void kernel_launch(void* const* d_in, const int* in_sizes, int n_in,
                              void* d_out, int out_size, void* d_ws, size_t ws_size,
                              hipStream_t stream)
{
    const float* src[4]  = {(const float*)d_in[0], (const float*)d_in[3],
                            (const float*)d_in[6], (const float*)d_in[9]};
    const float* q_feat  = (const float*)d_in[12];
    const float* q_pos   = (const float*)d_in[13];
    const float* q_ref   = (const float*)d_in[14];
    const float* so_w = (const float*)d_in[16];
    const float* so_b = (const float*)d_in[17];
    const float* aw_w = (const float*)d_in[18];
    const float* aw_b = (const float*)d_in[19];
    const float* vp_w = (const float*)d_in[20];
    const float* vp_b = (const float*)d_in[21];
    const float* op_w = (const float*)d_in[22];
    const float* op_b = (const float*)d_in[23];
    const float* n1_g = (const float*)d_in[24];
    const float* n1_b = (const float*)d_in[25];
    const float* l1_w = (const float*)d_in[26];
    const float* l1_b = (const float*)d_in[27];
    const float* l2_w = (const float*)d_in[28];
    const float* l2_b = (const float*)d_in[29];
    const float* n2_g = (const float*)d_in[30];
    const float* n2_b = (const float*)d_in[31];

    char* p = (char*)d_ws;
    auto alloc = [&](size_t bytes) { char* r = p; p += (bytes + 255) & ~255ULL; return r; };

    ushort* src_flat = (ushort*)alloc((size_t)BB * SS * DD * 2);
    ushort* v_buf6   = (ushort*)alloc((size_t)NL * BB * SS * DD * 2);
    ushort* q_bf     = (ushort*)alloc((size_t)BB * NQ * DD * 2);
    float*  offs     = (float*) alloc((size_t)BB * NQ * 256 * 4);
    float*  awb      = (float*) alloc((size_t)BB * NQ * 128 * 4);
    ushort* msda_bf  = (ushort*)alloc((size_t)BB * NQ * DD * 2);
    ushort* hbuf     = (ushort*)alloc((size_t)BB * NQ * DFF * 2);
    ushort* qf_bf    = (ushort*)alloc((size_t)BB * NQ * DD * 2);
    ushort* w_so     = (ushort*)alloc((size_t)NL * 256 * 256 * 2);
    ushort* w_aw     = (ushort*)alloc((size_t)NL * 128 * 256 * 2);
    ushort* w_vp     = (ushort*)alloc((size_t)NL * 256 * 256 * 2);
    ushort* w_op     = (ushort*)alloc((size_t)NL * 256 * 256 * 2);
    ushort* w_l1     = (ushort*)alloc((size_t)NL * DFF * 256 * 2);
    ushort* w_l2     = (ushort*)alloc((size_t)NL * 256 * DFF * 2);

    float* qf = (float*)d_out;   // residual stream lives in d_out

    cvt_all_kernel<<<4416, 256, 0, stream>>>(
        so_w, aw_w, vp_w, op_w, l1_w, l2_w,
        w_so, w_aw, w_vp, w_op, w_l1, w_l2);

    flatten_all_kernel<<<dim3(340, 4, 2), 256, 0, stream>>>(
        src[0], src[1], src[2], src[3], src_flat);

    const int RQ = BB * NQ;       // 8192 query rows
    const int RV = BB * SS;       // 43520 value rows

    // q_bf for layer 0: bf16(q_feat + q_pos)
    add_bf_kernel<<<RQ * DD / (256 * 4), 256, 0, stream>>>(q_feat, q_pos, q_bf, RQ * DD / 4);

    // all 6 layers' v-projections (z in grid), coalesced row-major out
    vp_gemm_kernel<<<dim3(RV / 128, 2, NL), 256, 0, stream>>>(
        src_flat, w_vp, vp_b, v_buf6);

    for (int l = 0; l < NL; ++l) {
        // fused q-projections: offsets (E 0..255) + attention logits (256..383)
        gemm_bf16<256, EPI_QF, 2><<<dim3(RQ / 64, 3), 256, 0, stream>>>(
            q_bf, w_so + (size_t)l * 256 * 256, so_b + (size_t)l * 256, offs, 256,
            w_aw + (size_t)l * 128 * 256, aw_b + (size_t)l * 128, awb);

        // bilinear sampling + weighted aggregation -> msda_bf (B,NQ,D)
        msda_kernel<<<(BB * NQ) / 4, 256, 0, stream>>>(
            v_buf6 + (size_t)l * BB * SS * DD, offs, awb, q_ref, msda_bf);

        // output projection + residual + LN1 (writes qf f32, qf_bf bf16)
        gemm_ln_kernel<256, false><<<RQ / 32, 256, 0, stream>>>(
            msda_bf, w_op + (size_t)l * 256 * 256, op_b + (size_t)l * 256,
            (l == 0 ? q_feat : qf), n1_g + l * 256, n1_b + l * 256,
            qf, qf_bf, nullptr);

        // FFN up + ReLU
        gemm_bf16<256, EPI_RELUB, 4><<<dim3(RQ / 128, DFF / 128), 256, 0, stream>>>(
            qf_bf, w_l1 + (size_t)l * DFF * 256, l1_b + (size_t)l * DFF, hbuf, DFF,
            nullptr, nullptr, nullptr);

        // FFN down + residual + LN2 (writes qf f32; q_bf = bf16(out + q_pos))
        gemm_ln_kernel<1024, true><<<RQ / 32, 256, 0, stream>>>(
            hbuf, w_l2 + (size_t)l * 256 * DFF, l2_b + (size_t)l * 256,
            qf, n2_g + l * 256, n2_b + l * 256,
            qf, q_bf, q_pos);
    }

    (void)in_sizes; (void)n_in; (void)out_size; (void)ws_size;
}